// Round 4
// baseline (1939.458 us; speedup 1.0000x reference)
//
#include <hip/hip_runtime.h>
#include <hip/hip_bf16.h>

#define BB 16
#define TT 16
#define CC 128
#define HW 1024             // 32*32
#define PIX (CC*HW)         // 131072
#define STOT ((long)BB*PIX) // 2M

// B-image geometry: tiles of 128 pixels x 32 k, stride-36 u32 words, quad-rotated
#define BTW 4608            // u32 words per B tile (128*36)
#define WI  147456          // u32 words per batch for a K=128 image (8 p-tiles * 4 k-tiles * BTW)
#define WZ  294912          // u32 words per batch for ZHZM (K=256 image)
#define XW  2359296         // u32 words per timestep of Xp (16 batches * WI)

typedef short short8 __attribute__((ext_vector_type(8)));
typedef float f32x4  __attribute__((ext_vector_type(4)));

__device__ __forceinline__ float sigf(float x) { return 1.0f / (1.0f + __expf(-x)); }
__device__ __forceinline__ float tanhf_fast(float x) {
    float ax = fabsf(x);
    float t = __expf(-2.0f * ax);
    float r = (1.0f - t) / (1.0f + t);
    return copysignf(r, x);
}

// ---- packed hi/lo bf16: uint32 = (bf16(x)<<16) | bf16(x - bf16(x)) ----
__device__ __forceinline__ unsigned pack_hl(float x) {
    unsigned u = __float_as_uint(x);
    unsigned hi = (u + 0x7fffu + ((u >> 16) & 1u)) >> 16;
    float r = x - __uint_as_float(hi << 16);
    unsigned v = __float_as_uint(r);
    unsigned lo = (v + 0x7fffu + ((v >> 16) & 1u)) >> 16;
    return (hi << 16) | lo;
}
__device__ __forceinline__ float unpack_hl(unsigned p) {
    return __uint_as_float(p & 0xffff0000u) + __uint_as_float(p << 16);
}
__device__ __forceinline__ unsigned short pack_bf16(float x) {
    unsigned u = __float_as_uint(x);
    return (unsigned short)((u + 0x7fffu + ((u >> 16) & 1u)) >> 16);
}
__device__ __forceinline__ float bf16f(unsigned short s) {
    return __uint_as_float(((unsigned)s) << 16);
}

// B-side split (activations packed u32 in LDS)
__device__ __forceinline__ void split_frag(uint4 a, uint4 b, short8& hi, short8& lo) {
    unsigned w[8] = {a.x, a.y, a.z, a.w, b.x, b.y, b.z, b.w};
    union U { unsigned u[4]; short8 s; } h, l;
    #pragma unroll
    for (int j = 0; j < 4; ++j) {
        h.u[j] = (w[2*j] >> 16)      | (w[2*j+1] & 0xffff0000u);
        l.u[j] = (w[2*j] & 0xffffu)  | (w[2*j+1] << 16);
    }
    hi = h.s; lo = l.s;
}

// B tile addr (u32 units): 128 rows x 32 k-words, stride 36, quad rotate (proven)
__device__ __forceinline__ int taddr(int row, int kw) {
    return row * 36 + ((((kw >> 2) + (row >> 2)) & 7) << 2) + (kw & 3);
}
// word index of element (pixel p, k-channel c) inside a per-batch B image with nkt k-tiles
__device__ __forceinline__ long bwidx(int p, int c, int nkt) {
    return (long)((p >> 7) * nkt + (c >> 5)) * BTW + taddr(p & 127, c & 31);
}

typedef __attribute__((address_space(3))) unsigned lds_u32_t;
typedef __attribute__((address_space(1))) const unsigned gbl_u32_t;
__device__ __forceinline__ void gld16(const void* g, unsigned* l) {
    __builtin_amdgcn_global_load_lds((gbl_u32_t*)g, (lds_u32_t*)l, 16, 0, 0);
}

// ---------------- MFMA GEMM with fused epilogues ----------------
// MODE 1: bf16 store (+ scalar bias[row])        -> outv = ushort* (linear)
// MODE 2: LSTM fuse: rows c*4+gate; stv=Cst(f32 linear), outv=Ha image (packed)
// MODE 3: final fuse: rows c*4+gate(3+pad); stv=mp image, outv=Hb image, Hout opt fp32 linear
// B-source: m0>=m_split -> imgB(kofs 0); k0>=k_split -> imgB(kofs k_split); else imgA.
// Both imgA/imgB are pre-swizzled B-tile images (packed hi/lo u32), DMA-staged.
// LO0: imgB region has lo==0 -> skip the ahi*blo MFMA pass there.
template<int MODE, int LO0>
__global__ __launch_bounds__(256, 2) void gemm_mfma(
    const unsigned* __restrict__ Wp, const float* __restrict__ bias,
    const unsigned* __restrict__ imgA, long wA,
    const unsigned* __restrict__ imgB, long wB, int nktB,
    int k_split, int m_split,
    void* __restrict__ outv, void* __restrict__ stv, float* __restrict__ Hout,
    int M, int K)
{
    __shared__ __align__(16) unsigned As[5120];   // 20480 B weight tile image
    __shared__ __align__(16) unsigned Bs[4608];   // 18432 B activation tile image

    const int b  = blockIdx.z;
    const int n0 = blockIdx.x * 128;
    const int m0 = blockIdx.y * 128;
    const int t  = threadIdx.x;
    const int lane = t & 63;
    const int w  = t >> 6;
    const int wm = w & 1, wn = w >> 1;
    const int g  = lane >> 4, pl = lane & 15;
    const int cb = ((g + (pl >> 2)) & 3) << 4;    // A-plane 16B-block rotation

    f32x4 acc[4][4] = {};

    for (int k0 = 0; k0 < K; k0 += 32) {
        // stage A (weights): 5 DMA rounds
        {
            const char* gA = (const char*)Wp +
                (size_t)((m0 >> 7) * (K >> 5) + (k0 >> 5)) * 20480;
            #pragma unroll
            for (int r = 0; r < 5; ++r)
                gld16(gA + r * 4096 + t * 16, As + r * 1024 + t * 4);
        }
        // stage B (activation image): 4.5 DMA rounds
        const bool useB = (m0 >= m_split) || (k0 >= k_split);
        {
            const int kc = useB ? (k0 - ((m0 >= m_split) ? 0 : k_split)) : k0;
            const unsigned* img = useB ? imgB : imgA;
            const long bw = useB ? wB : wA;
            const int nkt = useB ? nktB : 4;
            const char* gB = (const char*)(img + (long)b * bw +
                (long)((n0 >> 7) * nkt + (kc >> 5)) * BTW);
            #pragma unroll
            for (int r = 0; r < 4; ++r)
                gld16(gB + r * 4096 + t * 16, Bs + r * 1024 + t * 4);
            if (t < 128)
                gld16(gB + 16384 + t * 16, Bs + 4096 + t * 4);
        }
        __syncthreads();

        short8 ahi[4], alo[4], bhi[4], blo[4];
        #pragma unroll
        for (int mt = 0; mt < 4; ++mt) {
            int row = 64 * wm + 16 * mt + pl;
            const char* pa = (const char*)As + row * 80 + cb;
            ahi[mt] = *(const short8*)pa;
            alo[mt] = *(const short8*)(pa + 10240);
        }
        #pragma unroll
        for (int nt = 0; nt < 4; ++nt) {
            int prow = 64 * wn + 16 * nt + pl;
            uint4 w0 = *(const uint4*)(Bs + taddr(prow, 8 * g));
            uint4 w1 = *(const uint4*)(Bs + taddr(prow, 8 * g + 4));
            split_frag(w0, w1, bhi[nt], blo[nt]);
        }
        const bool skiplo = LO0 && useB;
        if (skiplo) {
            #pragma unroll
            for (int mt = 0; mt < 4; ++mt)
                #pragma unroll
                for (int nt = 0; nt < 4; ++nt) {
                    acc[mt][nt] = __builtin_amdgcn_mfma_f32_16x16x32_bf16(ahi[mt], bhi[nt], acc[mt][nt], 0, 0, 0);
                    acc[mt][nt] = __builtin_amdgcn_mfma_f32_16x16x32_bf16(alo[mt], bhi[nt], acc[mt][nt], 0, 0, 0);
                }
        } else {
            #pragma unroll
            for (int mt = 0; mt < 4; ++mt)
                #pragma unroll
                for (int nt = 0; nt < 4; ++nt) {
                    acc[mt][nt] = __builtin_amdgcn_mfma_f32_16x16x32_bf16(ahi[mt], bhi[nt], acc[mt][nt], 0, 0, 0);
                    acc[mt][nt] = __builtin_amdgcn_mfma_f32_16x16x32_bf16(ahi[mt], blo[nt], acc[mt][nt], 0, 0, 0);
                    acc[mt][nt] = __builtin_amdgcn_mfma_f32_16x16x32_bf16(alo[mt], bhi[nt], acc[mt][nt], 0, 0, 0);
                }
        }
        __syncthreads();
    }

    if (MODE == 1) {
        #pragma unroll
        for (int mt = 0; mt < 4; ++mt)
            #pragma unroll
            for (int r = 0; r < 4; ++r) {
                int row = m0 + 64 * wm + 16 * mt + 4 * g + r;
                float bb = bias[row];
                #pragma unroll
                for (int nt = 0; nt < 4; ++nt) {
                    int col = n0 + 64 * wn + 16 * nt + pl;
                    ((unsigned short*)outv)[((long)b * M + row) * HW + col] =
                        pack_bf16(acc[mt][nt][r] + bb);
                }
            }
    } else {
        // rows interleaved c*4+gate: one thread's f32x4 = all 4 gates of channel c
        const float4* bias4 = (const float4*)bias;
        unsigned* Hp = (unsigned*)outv;
        #pragma unroll
        for (int mt = 0; mt < 4; ++mt) {
            int c = (m0 >> 2) + 16 * wm + 4 * mt + g;
            float4 bb = bias4[c];
            #pragma unroll
            for (int nt = 0; nt < 4; ++nt) {
                int p = n0 + 64 * wn + 16 * nt + pl;
                long lidx = (long)b * PIX + (long)c * HW + p;       // linear (Cst, Hout)
                long widx = (long)b * WI + bwidx(p, c, 4);          // image (Ha/Hb/mp)
                float v0 = acc[mt][nt][0] + bb.x;
                float v1 = acc[mt][nt][1] + bb.y;
                float v2 = acc[mt][nt][2] + bb.z;
                float v3 = acc[mt][nt][3] + bb.w;
                if (MODE == 2) {
                    float* Cst = (float*)stv;
                    float cc = Cst[lidx] * sigf(v0) + sigf(v1) * tanhf_fast(v2);
                    Cst[lidx] = cc;
                    Hp[widx] = pack_hl(sigf(v3) * tanhf_fast(cc));
                } else {
                    unsigned* mp = (unsigned*)stv;
                    float ot = sigf(v0), gt = tanhf_fast(v1), it = sigf(v2);
                    float mo = unpack_hl(mp[widx]);
                    float mn = gt * it + (1.0f - it) * mo;
                    mp[widx] = pack_hl(mn);
                    float hv = ot * mn;
                    Hp[widx] = pack_hl(hv);
                    if (Hout) Hout[lidx] = hv;
                }
            }
        }
    }
}

// ---------------- attention: VKM bf16 [16][640][1024] -> ZHZM image u32 (lo=0) ----------------
__global__ __launch_bounds__(1024) void attn_kernel(
    const unsigned short* __restrict__ VKM, unsigned* __restrict__ Zimg)
{
    __shared__ float qs[32 * 33];
    const int tid = threadIdx.x;
    const int b = blockIdx.x >> 7, c = blockIdx.x & 127;
    const long base = ((long)b * 640 + c) * HW;

    qs[(tid >> 5) * 33 + (tid & 31)] = bf16f(VKM[base + 256l * HW + tid]);
    __syncthreads();

    const int i = tid >> 5, j = tid & 31;
    float qhT = qs[j * 33 + i];
    float vh  = bf16f(VKM[base + tid]);
    float kh  = bf16f(VKM[base + 128l * HW + tid]);
    float km  = bf16f(VKM[base + 384l * HW + tid]);
    float vm  = bf16f(VKM[base + 512l * HW + tid]);

    float sh = kh * qhT, sm = qhT * km;
    float mh = sh, mm = sm;
    #pragma unroll
    for (int o = 16; o > 0; o >>= 1) {
        mh = fmaxf(mh, __shfl_xor(mh, o, 32));
        mm = fmaxf(mm, __shfl_xor(mm, o, 32));
    }
    float eh = __expf(sh - mh), em = __expf(sm - mm);
    float s1 = eh, s2 = em;
    #pragma unroll
    for (int o = 16; o > 0; o >>= 1) {
        s1 += __shfl_xor(s1, o, 32);
        s2 += __shfl_xor(s2, o, 32);
    }
    long t1 = (long)b * WZ + bwidx(tid, c, 8);          // zh at k=c
    Zimg[t1]            = ((unsigned)pack_bf16(vh * (eh / s1))) << 16;
    Zimg[t1 + 4 * BTW]  = ((unsigned)pack_bf16(vm * (em / s2))) << 16;  // zm at k=c+128
}

// ---------------- pack x_t into B-image format (LDS-transpose tiler) ----------------
// block = (tloc, bz, ptile); processes 128 p x 128 c in two 64-c halves
// NOTE x layout is [B][T][C][HW] — batch-major!
__global__ __launch_bounds__(256) void pack_x(
    const float* __restrict__ x, unsigned* __restrict__ Xp, int tstart)
{
    __shared__ float lx[64 * 133];
    const int blk = blockIdx.x;
    const int pt = blk & 7, bz = (blk >> 3) & 15, tloc = blk >> 7;
    const float* src = x + ((long)bz * TT + (tstart + tloc)) * PIX + pt * 128;
    unsigned* dst = Xp + (long)tloc * XW + (long)bz * WI + (long)pt * (4 * BTW);

    for (int h = 0; h < 2; ++h) {
        #pragma unroll
        for (int i = 0; i < 8; ++i) {
            int idx = threadIdx.x + 256 * i;        // 0..2047
            int c = idx >> 5, q = idx & 31;
            float4 f = *(const float4*)(src + (long)(64 * h + c) * HW + 4 * q);
            lx[c * 133 + 4 * q    ] = f.x;
            lx[c * 133 + 4 * q + 1] = f.y;
            lx[c * 133 + 4 * q + 2] = f.z;
            lx[c * 133 + 4 * q + 3] = f.w;
        }
        __syncthreads();
        #pragma unroll
        for (int kt2 = 0; kt2 < 2; ++kt2) {
            int kt = 2 * h + kt2;
            #pragma unroll
            for (int i = 0; i < 4; ++i) {
                int idx = threadIdx.x + 256 * i;    // 0..1023
                int row = idx >> 3, qq = idx & 7;
                uint4 o;
                o.x = pack_hl(lx[(kt2 * 32 + 4 * qq    ) * 133 + row]);
                o.y = pack_hl(lx[(kt2 * 32 + 4 * qq + 1) * 133 + row]);
                o.z = pack_hl(lx[(kt2 * 32 + 4 * qq + 2) * 133 + row]);
                o.w = pack_hl(lx[(kt2 * 32 + 4 * qq + 3) * 133 + row]);
                *(uint4*)(dst + (long)kt * BTW + row * 36 +
                          (((qq + (row >> 2)) & 7) << 2)) = o;
            }
        }
        __syncthreads();
    }
}

// ---------------- one-shot setup: build pre-swizzled hi/lo weight tile images ----------------
__device__ __forceinline__ void wimg(unsigned short* img, int Ktiles, int r, int k, float v) {
    int tile = (r >> 7) * Ktiles + (k >> 5);
    int row = r & 127, ks = k & 31;
    unsigned short* p = img + (size_t)tile * 10240;   // 10240 shorts = 20480 B per tile
    int off = row * 40 + ((((ks >> 3) + (row >> 2)) & 3) << 3) + (ks & 7);
    unsigned u = __float_as_uint(v);
    unsigned short hi = (unsigned short)((u + 0x7fffu + ((u >> 16) & 1u)) >> 16);
    float rr = v - __uint_as_float((unsigned)hi << 16);
    unsigned u2 = __float_as_uint(rr);
    unsigned short lo = (unsigned short)((u2 + 0x7fffu + ((u2 >> 16) & 1u)) >> 16);
    p[off] = hi;
    p[off + 5120] = lo;                               // lo plane at +10240 B
}

__global__ __launch_bounds__(256) void setup_all(
    const float* __restrict__ W5, const float* __restrict__ W8, const float* __restrict__ b8,
    unsigned short* __restrict__ Wp5i,
    unsigned short* __restrict__ Wgi, float* __restrict__ bg4,
    unsigned short* __restrict__ Woi, float* __restrict__ bo4)
{
    int idx = blockIdx.x * 256 + threadIdx.x;
    if (idx < 81920) {                       // W5 [640][128] -> Wp5 image (Ktiles=4)
        int r = idx >> 7, k = idx & 127;
        wimg(Wp5i, 4, r, k, W5[idx]);
        return;
    }
    idx -= 81920;
    if (idx < 131072) {                      // Wg: rows c*4+gate, convs 10..13, K=256 (Ktiles=8)
        int rr = idx >> 8, k = idx & 255;
        int c = rr >> 2, gg = rr & 3;
        wimg(Wgi, 8, rr, k, W8[((long)(4 + gg) * 128 + c) * 256 + k]);
        if (k == 0) bg4[rr] = b8[(4 + gg) * 128 + c];
        return;
    }
    idx -= 131072;                           // Wo: 512 rows x 384, conv6 folded (Ktiles=12)
    if (idx >= 512 * 384) return;
    int rr = idx / 384, k = idx - rr * 384;
    int c = rr >> 2, gg = rr & 3;
    float wv = 0.0f;
    if (gg < 3) {
        const float* wr = W8 + ((long)(1 + gg) * 128 + c) * 256;
        if (k < 128) {
            wv = wr[k];
        } else {
            int i = k - 128;
            float s = 0.0f;
            for (int j = 0; j < 128; ++j)
                s += wr[128 + j] * W8[(long)j * 256 + i];   // Wz = W8[0]
            wv = s;
        }
    }
    wimg(Woi, 12, rr, k, wv);
    if (k == 0) {
        float bb = 0.0f;
        if (gg < 3) {
            bb = b8[(1 + gg) * 128 + c];
            const float* wr = W8 + ((long)(1 + gg) * 128 + c) * 256;
            for (int j = 0; j < 128; ++j) bb += wr[128 + j] * b8[j];  // bz = b8[0]
        }
        bo4[rr] = bb;
    }
}

extern "C" void kernel_launch(void* const* d_in, const int* in_sizes, int n_in,
                              void* d_out, int out_size, void* d_ws, size_t ws_size,
                              hipStream_t stream)
{
    const float* x  = (const float*)d_in[0];   // [16][16][128][1024]  (B-major)
    const float* c0 = (const float*)d_in[1];
    const float* W5 = (const float*)d_in[2];   // [640][128]
    const float* b5 = (const float*)d_in[3];   // [640]
    const float* W8 = (const float*)d_in[4];   // [8][128][256]
    const float* b8 = (const float*)d_in[5];   // [8][128]
    float* out = (float*)d_out;

    const long S = STOT;
    unsigned* Ha   = (unsigned*)d_ws;                   // 16*WI (image)
    unsigned* Hb   = Ha + 16l * WI;                     // 16*WI (image)
    unsigned* mp   = Hb + 16l * WI;                     // 16*WI (image)
    float*    Cst  = (float*)(mp + 16l * WI);           // S fp32 linear
    unsigned short* Wp5i = (unsigned short*)(Cst + S);  // 20 tiles * 10240 shorts
    unsigned short* Wgi  = Wp5i + 20 * 10240;           // 32 tiles
    unsigned short* Woi  = Wgi + 32 * 10240;            // 48 tiles
    float*    bg4  = (float*)(Woi + 48 * 10240);        // 512
    float*    bo4  = bg4 + 512;                         // 512
    unsigned short* VKM = (unsigned short*)(bo4 + 512); // 5S bf16 linear
    unsigned* Zimg = (unsigned*)(VKM + 5 * S);          // 16*WZ (image)
    unsigned* Xp   = Zimg + 16l * WZ;                   // 16*XW full, or XW slot

    const bool havex =
        ((char*)(Xp + 16l * XW) - (char*)d_ws) <= (long)ws_size;

    hipMemsetAsync(Hb, 0, 16l * WI * 4, stream);
    hipMemsetAsync(mp, 0, 16l * WI * 4, stream);
    hipMemcpyAsync(Cst, c0, S * sizeof(float), hipMemcpyDeviceToDevice, stream);

    setup_all<<<1600, dim3(256), 0, stream>>>(W5, W8, b8, Wp5i, Wgi, bg4, Woi, bo4);
    if (havex)
        pack_x<<<2048, dim3(256), 0, stream>>>(x, Xp, 0);

    const int BIG = 1 << 30;
    const dim3 blk(256);
    for (int t = 0; t < TT; ++t) {
        if (!havex)
            pack_x<<<128, dim3(256), 0, stream>>>(x, Xp, t);
        const unsigned* Xpt = Xp + (havex ? (long)t * XW : 0l);

        // gates = Wg * [Hb ; x_t], fused LSTM -> Cst, Ha image  (M=512, K=256)
        gemm_mfma<2, 0><<<dim3(8, 4, 16), blk, 0, stream>>>(
            (const unsigned*)Wgi, bg4, Hb, (long)WI, Xpt, (long)WI, 4,
            128, BIG, Ha, Cst, nullptr, 512, 256);

        // vh,kh,qh (Ha) + km,vm (mp)   (M=640, K=128) -> VKM bf16 linear
        gemm_mfma<1, 0><<<dim3(8, 5, 16), blk, 0, stream>>>(
            (const unsigned*)Wp5i, b5, Ha, (long)WI, mp, (long)WI, 4,
            BIG, 384, VKM, nullptr, nullptr, 640, 128);

        attn_kernel<<<2048, dim3(1024), 0, stream>>>(VKM, Zimg);

        // o,g,i = Wo * [Ha ; Zimg] (conv6 folded), fused final -> mp, Hb (+out)
        gemm_mfma<3, 1><<<dim3(8, 4, 16), blk, 0, stream>>>(
            (const unsigned*)Woi, bo4, Ha, (long)WI, Zimg, (long)WZ, 8,
            128, BIG, Hb, mp, (t == TT - 1) ? out : nullptr, 512, 384);
    }
}

// Round 5
// 1852.291 us; speedup vs baseline: 1.0471x; 1.0471x over previous
//
#include <hip/hip_runtime.h>
#include <hip/hip_bf16.h>

#define BB 16
#define TT 16
#define CC 128
#define HW 1024             // 32*32
#define PIX (CC*HW)         // 131072
#define STOT ((long)BB*PIX) // 2M

// B-image geometry: tiles of 128 pixels x 32 k, stride-36 u32 words, quad-rotated
#define BTW 4608            // u32 words per B tile (128*36)
#define WI  147456          // u32 words per batch for a K=128 image (8 p-tiles * 4 k-tiles * BTW)
#define WZ  294912          // u32 words per batch for ZHZM (K=256 image)
#define XW  2359296         // u32 words per timestep of Xp (16 batches * WI)

typedef short short8 __attribute__((ext_vector_type(8)));
typedef float f32x4  __attribute__((ext_vector_type(4)));

__device__ __forceinline__ float sigf(float x) { return 1.0f / (1.0f + __expf(-x)); }
__device__ __forceinline__ float tanhf_fast(float x) {
    float ax = fabsf(x);
    float t = __expf(-2.0f * ax);
    float r = (1.0f - t) / (1.0f + t);
    return copysignf(r, x);
}

// ---- packed hi/lo bf16: uint32 = (bf16(x)<<16) | bf16(x - bf16(x)) ----
__device__ __forceinline__ unsigned pack_hl(float x) {
    unsigned u = __float_as_uint(x);
    unsigned hi = (u + 0x7fffu + ((u >> 16) & 1u)) >> 16;
    float r = x - __uint_as_float(hi << 16);
    unsigned v = __float_as_uint(r);
    unsigned lo = (v + 0x7fffu + ((v >> 16) & 1u)) >> 16;
    return (hi << 16) | lo;
}
__device__ __forceinline__ float unpack_hl(unsigned p) {
    return __uint_as_float(p & 0xffff0000u) + __uint_as_float(p << 16);
}
__device__ __forceinline__ unsigned short pack_bf16(float x) {
    unsigned u = __float_as_uint(x);
    return (unsigned short)((u + 0x7fffu + ((u >> 16) & 1u)) >> 16);
}
__device__ __forceinline__ float bf16f(unsigned short s) {
    return __uint_as_float(((unsigned)s) << 16);
}

// B-side split (activations packed u32 in LDS)
__device__ __forceinline__ void split_frag(uint4 a, uint4 b, short8& hi, short8& lo) {
    unsigned w[8] = {a.x, a.y, a.z, a.w, b.x, b.y, b.z, b.w};
    union U { unsigned u[4]; short8 s; } h, l;
    #pragma unroll
    for (int j = 0; j < 4; ++j) {
        h.u[j] = (w[2*j] >> 16)      | (w[2*j+1] & 0xffff0000u);
        l.u[j] = (w[2*j] & 0xffffu)  | (w[2*j+1] << 16);
    }
    hi = h.s; lo = l.s;
}

// B tile addr (u32 units): 128 rows x 32 k-words, stride 36, quad rotate (proven)
__device__ __forceinline__ int taddr(int row, int kw) {
    return row * 36 + ((((kw >> 2) + (row >> 2)) & 7) << 2) + (kw & 3);
}
// word index of element (pixel p, k-channel c) inside a per-batch B image with nkt k-tiles
__device__ __forceinline__ long bwidx(int p, int c, int nkt) {
    return (long)((p >> 7) * nkt + (c >> 5)) * BTW + taddr(p & 127, c & 31);
}

typedef __attribute__((address_space(3))) unsigned lds_u32_t;
typedef __attribute__((address_space(1))) const unsigned gbl_u32_t;
__device__ __forceinline__ void gld16(const void* g, unsigned* l) {
    __builtin_amdgcn_global_load_lds((gbl_u32_t*)g, (lds_u32_t*)l, 16, 0, 0);
}

// ---------------- MFMA GEMM with fused epilogues ----------------
// MODE 1: bf16 store (+ scalar bias[row])        -> outv = ushort* (linear)
// MODE 2: LSTM fuse: rows c*4+gate; stv=Cst(f32 linear), outv=Ha image (packed)
// MODE 3: final fuse: rows c*4+gate(3+pad); stv=mp image, outv=Hb image, Hout opt fp32 linear
// B-source: m0>=m_split -> imgB(kofs 0); k0>=k_split -> imgB(kofs k_split); else imgA.
// Both imgA/imgB are pre-swizzled B-tile images (packed hi/lo u32), DMA-staged.
// LO0: imgB region has lo==0 -> skip the ahi*blo MFMA pass there.
template<int MODE, int LO0>
__global__ __launch_bounds__(256, 2) void gemm_mfma(
    const unsigned* __restrict__ Wp, const float* __restrict__ bias,
    const unsigned* __restrict__ imgA, long wA,
    const unsigned* __restrict__ imgB, long wB, int nktB,
    int k_split, int m_split,
    void* __restrict__ outv, void* __restrict__ stv, float* __restrict__ Hout,
    int M, int K)
{
    __shared__ __align__(16) unsigned As[5120];   // 20480 B weight tile image
    __shared__ __align__(16) unsigned Bs[4608];   // 18432 B activation tile image

    const int b  = blockIdx.z;
    const int n0 = blockIdx.x * 128;
    const int m0 = blockIdx.y * 128;
    const int t  = threadIdx.x;
    const int lane = t & 63;
    const int w  = t >> 6;
    const int wm = w & 1, wn = w >> 1;
    const int g  = lane >> 4, pl = lane & 15;
    const int cb = ((g + (pl >> 2)) & 3) << 4;    // A-plane 16B-block rotation

    f32x4 acc[4][4] = {};

    for (int k0 = 0; k0 < K; k0 += 32) {
        // stage A (weights): 5 DMA rounds
        {
            const char* gA = (const char*)Wp +
                (size_t)((m0 >> 7) * (K >> 5) + (k0 >> 5)) * 20480;
            #pragma unroll
            for (int r = 0; r < 5; ++r)
                gld16(gA + r * 4096 + t * 16, As + r * 1024 + t * 4);
        }
        // stage B (activation image): 4.5 DMA rounds
        const bool useB = (m0 >= m_split) || (k0 >= k_split);
        {
            const int kc = useB ? (k0 - ((m0 >= m_split) ? 0 : k_split)) : k0;
            const unsigned* img = useB ? imgB : imgA;
            const long bw = useB ? wB : wA;
            const int nkt = useB ? nktB : 4;
            const char* gB = (const char*)(img + (long)b * bw +
                (long)((n0 >> 7) * nkt + (kc >> 5)) * BTW);
            #pragma unroll
            for (int r = 0; r < 4; ++r)
                gld16(gB + r * 4096 + t * 16, Bs + r * 1024 + t * 4);
            if (t < 128)
                gld16(gB + 16384 + t * 16, Bs + 4096 + t * 4);
        }
        __syncthreads();

        short8 ahi[4], alo[4], bhi[4], blo[4];
        #pragma unroll
        for (int mt = 0; mt < 4; ++mt) {
            int row = 64 * wm + 16 * mt + pl;
            const char* pa = (const char*)As + row * 80 + cb;
            ahi[mt] = *(const short8*)pa;
            alo[mt] = *(const short8*)(pa + 10240);
        }
        #pragma unroll
        for (int nt = 0; nt < 4; ++nt) {
            int prow = 64 * wn + 16 * nt + pl;
            uint4 w0 = *(const uint4*)(Bs + taddr(prow, 8 * g));
            uint4 w1 = *(const uint4*)(Bs + taddr(prow, 8 * g + 4));
            split_frag(w0, w1, bhi[nt], blo[nt]);
        }
        const bool skiplo = LO0 && useB;
        if (skiplo) {
            #pragma unroll
            for (int mt = 0; mt < 4; ++mt)
                #pragma unroll
                for (int nt = 0; nt < 4; ++nt) {
                    acc[mt][nt] = __builtin_amdgcn_mfma_f32_16x16x32_bf16(ahi[mt], bhi[nt], acc[mt][nt], 0, 0, 0);
                    acc[mt][nt] = __builtin_amdgcn_mfma_f32_16x16x32_bf16(alo[mt], bhi[nt], acc[mt][nt], 0, 0, 0);
                }
        } else {
            #pragma unroll
            for (int mt = 0; mt < 4; ++mt)
                #pragma unroll
                for (int nt = 0; nt < 4; ++nt) {
                    acc[mt][nt] = __builtin_amdgcn_mfma_f32_16x16x32_bf16(ahi[mt], bhi[nt], acc[mt][nt], 0, 0, 0);
                    acc[mt][nt] = __builtin_amdgcn_mfma_f32_16x16x32_bf16(ahi[mt], blo[nt], acc[mt][nt], 0, 0, 0);
                    acc[mt][nt] = __builtin_amdgcn_mfma_f32_16x16x32_bf16(alo[mt], bhi[nt], acc[mt][nt], 0, 0, 0);
                }
        }
        __syncthreads();
    }

    if (MODE == 1) {
        #pragma unroll
        for (int mt = 0; mt < 4; ++mt)
            #pragma unroll
            for (int r = 0; r < 4; ++r) {
                int row = m0 + 64 * wm + 16 * mt + 4 * g + r;
                float bb = bias[row];
                #pragma unroll
                for (int nt = 0; nt < 4; ++nt) {
                    int col = n0 + 64 * wn + 16 * nt + pl;
                    ((unsigned short*)outv)[((long)b * M + row) * HW + col] =
                        pack_bf16(acc[mt][nt][r] + bb);
                }
            }
    } else {
        // rows interleaved c*4+gate: one thread's f32x4 = all 4 gates of channel c
        const float4* bias4 = (const float4*)bias;
        unsigned* Hp = (unsigned*)outv;
        #pragma unroll
        for (int mt = 0; mt < 4; ++mt) {
            int c = (m0 >> 2) + 16 * wm + 4 * mt + g;
            float4 bb = bias4[c];
            #pragma unroll
            for (int nt = 0; nt < 4; ++nt) {
                int p = n0 + 64 * wn + 16 * nt + pl;
                long lidx = (long)b * PIX + (long)c * HW + p;       // linear (Cst, Hout)
                long widx = (long)b * WI + bwidx(p, c, 4);          // image (Ha/Hb/mp)
                float v0 = acc[mt][nt][0] + bb.x;
                float v1 = acc[mt][nt][1] + bb.y;
                float v2 = acc[mt][nt][2] + bb.z;
                float v3 = acc[mt][nt][3] + bb.w;
                if (MODE == 2) {
                    float* Cst = (float*)stv;
                    float cc = Cst[lidx] * sigf(v0) + sigf(v1) * tanhf_fast(v2);
                    Cst[lidx] = cc;
                    Hp[widx] = pack_hl(sigf(v3) * tanhf_fast(cc));
                } else {
                    unsigned* mp = (unsigned*)stv;
                    float ot = sigf(v0), gt = tanhf_fast(v1), it = sigf(v2);
                    float mo = unpack_hl(mp[widx]);
                    float mn = gt * it + (1.0f - it) * mo;
                    mp[widx] = pack_hl(mn);
                    float hv = ot * mn;
                    Hp[widx] = pack_hl(hv);
                    if (Hout) Hout[lidx] = hv;
                }
            }
        }
    }
}

// ---------------- attention: VKM bf16 [16][640][1024] -> ZHZM image u32 (lo=0) ----------------
__global__ __launch_bounds__(1024) void attn_kernel(
    const unsigned short* __restrict__ VKM, unsigned* __restrict__ Zimg)
{
    __shared__ float qs[32 * 33];
    const int tid = threadIdx.x;
    const int b = blockIdx.x >> 7, c = blockIdx.x & 127;
    const long base = ((long)b * 640 + c) * HW;

    qs[(tid >> 5) * 33 + (tid & 31)] = bf16f(VKM[base + 256l * HW + tid]);
    __syncthreads();

    const int i = tid >> 5, j = tid & 31;
    float qhT = qs[j * 33 + i];
    float vh  = bf16f(VKM[base + tid]);
    float kh  = bf16f(VKM[base + 128l * HW + tid]);
    float km  = bf16f(VKM[base + 384l * HW + tid]);
    float vm  = bf16f(VKM[base + 512l * HW + tid]);

    float sh = kh * qhT, sm = qhT * km;
    float mh = sh, mm = sm;
    #pragma unroll
    for (int o = 16; o > 0; o >>= 1) {
        mh = fmaxf(mh, __shfl_xor(mh, o, 32));
        mm = fmaxf(mm, __shfl_xor(mm, o, 32));
    }
    float eh = __expf(sh - mh), em = __expf(sm - mm);
    float s1 = eh, s2 = em;
    #pragma unroll
    for (int o = 16; o > 0; o >>= 1) {
        s1 += __shfl_xor(s1, o, 32);
        s2 += __shfl_xor(s2, o, 32);
    }
    long t1 = (long)b * WZ + bwidx(tid, c, 8);          // zh at k=c
    Zimg[t1]            = ((unsigned)pack_bf16(vh * (eh / s1))) << 16;
    Zimg[t1 + 4 * BTW]  = ((unsigned)pack_bf16(vm * (em / s2))) << 16;  // zm at k=c+128
}

// ---------------- pack x_t into B-image format, DEST-LINEAR writer ----------------
// block = (tloc, h, bz, pt): pt=blk&7, bz=(blk>>3)&15, h=(blk>>7)&1, tloc=blk>>8
// Stages 64 chans x 128 px in LDS (coalesced float4 reads), then writes the two
// corresponding k-tiles of the image as contiguous 16B chunks (pads written as 0),
// applying the inverse block rotation kb = (c4 - row>>2) & 7.
// NOTE x layout is [B][T][C][HW] — batch-major!
__global__ __launch_bounds__(256) void pack_x(
    const float* __restrict__ x, unsigned* __restrict__ Xp, int tstart)
{
    __shared__ float lx[64 * 133];
    const int blk = blockIdx.x;
    const int pt = blk & 7, bz = (blk >> 3) & 15, h = (blk >> 7) & 1, tloc = blk >> 8;
    const float* src = x + ((long)bz * TT + (tstart + tloc)) * PIX +
                       (long)(64 * h) * HW + pt * 128;
    unsigned* dst = Xp + (long)tloc * XW + (long)bz * WI +
                    (long)pt * (4 * BTW) + (long)(2 * h) * BTW;

    #pragma unroll
    for (int i = 0; i < 8; ++i) {
        int idx = threadIdx.x + 256 * i;        // 0..2047 -> 64 chans x 128 px
        int cl = idx >> 5, q = idx & 31;
        float4 f = *(const float4*)(src + (long)cl * HW + 4 * q);
        lx[cl * 133 + 4 * q    ] = f.x;
        lx[cl * 133 + 4 * q + 1] = f.y;
        lx[cl * 133 + 4 * q + 2] = f.z;
        lx[cl * 133 + 4 * q + 3] = f.w;
    }
    __syncthreads();
    #pragma unroll
    for (int kt2 = 0; kt2 < 2; ++kt2) {
        uint4* dt = (uint4*)(dst + (long)kt2 * BTW);
        #pragma unroll
        for (int it = 0; it < 5; ++it) {
            int w4 = it * 256 + threadIdx.x;    // uint4 index in tile, 1152 total
            if (w4 < 1152) {
                int row = w4 / 9, c4 = w4 - row * 9;
                uint4 o;
                if (c4 == 8) {                  // pad block: write zeros (full coverage)
                    o.x = o.y = o.z = o.w = 0;
                } else {
                    int kb = (c4 - (row >> 2)) & 7;
                    const float* lp = lx + (kt2 * 32 + kb * 4) * 133 + row;
                    o.x = pack_hl(lp[0]);
                    o.y = pack_hl(lp[133]);
                    o.z = pack_hl(lp[266]);
                    o.w = pack_hl(lp[399]);
                }
                dt[w4] = o;
            }
        }
    }
}

// ---------------- one-shot setup: build pre-swizzled hi/lo weight tile images ----------------
__device__ __forceinline__ void wimg(unsigned short* img, int Ktiles, int r, int k, float v) {
    int tile = (r >> 7) * Ktiles + (k >> 5);
    int row = r & 127, ks = k & 31;
    unsigned short* p = img + (size_t)tile * 10240;   // 10240 shorts = 20480 B per tile
    int off = row * 40 + ((((ks >> 3) + (row >> 2)) & 3) << 3) + (ks & 7);
    unsigned u = __float_as_uint(v);
    unsigned short hi = (unsigned short)((u + 0x7fffu + ((u >> 16) & 1u)) >> 16);
    float rr = v - __uint_as_float((unsigned)hi << 16);
    unsigned u2 = __float_as_uint(rr);
    unsigned short lo = (unsigned short)((u2 + 0x7fffu + ((u2 >> 16) & 1u)) >> 16);
    p[off] = hi;
    p[off + 5120] = lo;                               // lo plane at +10240 B
}

__global__ __launch_bounds__(256) void setup_all(
    const float* __restrict__ W5, const float* __restrict__ W8, const float* __restrict__ b8,
    unsigned short* __restrict__ Wp5i,
    unsigned short* __restrict__ Wgi, float* __restrict__ bg4,
    unsigned short* __restrict__ Woi, float* __restrict__ bo4)
{
    int idx = blockIdx.x * 256 + threadIdx.x;
    if (idx < 81920) {                       // W5 [640][128] -> Wp5 image (Ktiles=4)
        int r = idx >> 7, k = idx & 127;
        wimg(Wp5i, 4, r, k, W5[idx]);
        return;
    }
    idx -= 81920;
    if (idx < 131072) {                      // Wg: rows c*4+gate, convs 10..13, K=256 (Ktiles=8)
        int rr = idx >> 8, k = idx & 255;
        int c = rr >> 2, gg = rr & 3;
        wimg(Wgi, 8, rr, k, W8[((long)(4 + gg) * 128 + c) * 256 + k]);
        if (k == 0) bg4[rr] = b8[(4 + gg) * 128 + c];
        return;
    }
    idx -= 131072;                           // Wo: 512 rows x 384, conv6 folded (Ktiles=12)
    if (idx >= 512 * 384) return;
    int rr = idx / 384, k = idx - rr * 384;
    int c = rr >> 2, gg = rr & 3;
    float wv = 0.0f;
    if (gg < 3) {
        const float* wr = W8 + ((long)(1 + gg) * 128 + c) * 256;
        if (k < 128) {
            wv = wr[k];
        } else {
            int i = k - 128;
            float s = 0.0f;
            for (int j = 0; j < 128; ++j)
                s += wr[128 + j] * W8[(long)j * 256 + i];   // Wz = W8[0]
            wv = s;
        }
    }
    wimg(Woi, 12, rr, k, wv);
    if (k == 0) {
        float bb = 0.0f;
        if (gg < 3) {
            bb = b8[(1 + gg) * 128 + c];
            const float* wr = W8 + ((long)(1 + gg) * 128 + c) * 256;
            for (int j = 0; j < 128; ++j) bb += wr[128 + j] * b8[j];  // bz = b8[0]
        }
        bo4[rr] = bb;
    }
}

extern "C" void kernel_launch(void* const* d_in, const int* in_sizes, int n_in,
                              void* d_out, int out_size, void* d_ws, size_t ws_size,
                              hipStream_t stream)
{
    const float* x  = (const float*)d_in[0];   // [16][16][128][1024]  (B-major)
    const float* c0 = (const float*)d_in[1];
    const float* W5 = (const float*)d_in[2];   // [640][128]
    const float* b5 = (const float*)d_in[3];   // [640]
    const float* W8 = (const float*)d_in[4];   // [8][128][256]
    const float* b8 = (const float*)d_in[5];   // [8][128]
    float* out = (float*)d_out;

    const long S = STOT;
    unsigned* Ha   = (unsigned*)d_ws;                   // 16*WI (image)
    unsigned* Hb   = Ha + 16l * WI;                     // 16*WI (image)
    unsigned* mp   = Hb + 16l * WI;                     // 16*WI (image)
    float*    Cst  = (float*)(mp + 16l * WI);           // S fp32 linear
    unsigned short* Wp5i = (unsigned short*)(Cst + S);  // 20 tiles * 10240 shorts
    unsigned short* Wgi  = Wp5i + 20 * 10240;           // 32 tiles
    unsigned short* Woi  = Wgi + 32 * 10240;            // 48 tiles
    float*    bg4  = (float*)(Woi + 48 * 10240);        // 512
    float*    bo4  = bg4 + 512;                         // 512
    unsigned short* VKM = (unsigned short*)(bo4 + 512); // 5S bf16 linear
    unsigned* Zimg = (unsigned*)(VKM + 5 * S);          // 16*WZ (image)
    unsigned* Xp   = Zimg + 16l * WZ;                   // 16*XW full, or XW slot

    const bool havex =
        ((char*)(Xp + 16l * XW) - (char*)d_ws) <= (long)ws_size;

    hipMemsetAsync(Hb, 0, 16l * WI * 4, stream);
    hipMemsetAsync(mp, 0, 16l * WI * 4, stream);
    hipMemcpyAsync(Cst, c0, S * sizeof(float), hipMemcpyDeviceToDevice, stream);

    setup_all<<<1600, dim3(256), 0, stream>>>(W5, W8, b8, Wp5i, Wgi, bg4, Woi, bo4);
    if (havex)
        pack_x<<<4096, dim3(256), 0, stream>>>(x, Xp, 0);

    const int BIG = 1 << 30;
    const dim3 blk(256);
    for (int t = 0; t < TT; ++t) {
        if (!havex)
            pack_x<<<256, dim3(256), 0, stream>>>(x, Xp, t);
        const unsigned* Xpt = Xp + (havex ? (long)t * XW : 0l);

        // gates = Wg * [Hb ; x_t], fused LSTM -> Cst, Ha image  (M=512, K=256)
        gemm_mfma<2, 0><<<dim3(8, 4, 16), blk, 0, stream>>>(
            (const unsigned*)Wgi, bg4, Hb, (long)WI, Xpt, (long)WI, 4,
            128, BIG, Ha, Cst, nullptr, 512, 256);

        // vh,kh,qh (Ha) + km,vm (mp)   (M=640, K=128) -> VKM bf16 linear
        gemm_mfma<1, 0><<<dim3(8, 5, 16), blk, 0, stream>>>(
            (const unsigned*)Wp5i, b5, Ha, (long)WI, mp, (long)WI, 4,
            BIG, 384, VKM, nullptr, nullptr, 640, 128);

        attn_kernel<<<2048, dim3(1024), 0, stream>>>(VKM, Zimg);

        // o,g,i = Wo * [Ha ; Zimg] (conv6 folded), fused final -> mp, Hb (+out)
        gemm_mfma<3, 1><<<dim3(8, 4, 16), blk, 0, stream>>>(
            (const unsigned*)Woi, bo4, Ha, (long)WI, Zimg, (long)WZ, 8,
            128, BIG, Hb, mp, (t == TT - 1) ? out : nullptr, 512, 384);
    }
}

// Round 6
// 1488.614 us; speedup vs baseline: 1.3029x; 1.2443x over previous
//
#include <hip/hip_runtime.h>
#include <hip/hip_bf16.h>

#define BB 16
#define TT 16
#define CC 128
#define HW 1024             // 32*32
#define PIX (CC*HW)         // 131072
#define STOT ((long)BB*PIX) // 2M

// B-image geometry v2: tiles of 128 pixels x 32 k, KBLOCK-MAJOR, no pads.
// word(row, kw) = (kw>>2)*512 + phys(row,kb)*4 + (kw&3), phys = (row+16*kb)&127
#define BTW 4096            // u32 words per B tile
#define WI  131072          // u32 words per batch, K=128 image (8 p-tiles * 4 k-tiles)
#define WZ  262144          // u32 words per batch, K=256 image (ZHZM)
#define XW  2097152         // u32 words per timestep of Xp (16 batches * WI)

typedef short short8 __attribute__((ext_vector_type(8)));
typedef float f32x4  __attribute__((ext_vector_type(4)));

__device__ __forceinline__ float sigf(float x) { return 1.0f / (1.0f + __expf(-x)); }
__device__ __forceinline__ float tanhf_fast(float x) {
    float ax = fabsf(x);
    float t = __expf(-2.0f * ax);
    float r = (1.0f - t) / (1.0f + t);
    return copysignf(r, x);
}

// ---- packed hi/lo bf16: uint32 = (bf16(x)<<16) | bf16(x - bf16(x)) ----
__device__ __forceinline__ unsigned pack_hl(float x) {
    unsigned u = __float_as_uint(x);
    unsigned hi = (u + 0x7fffu + ((u >> 16) & 1u)) >> 16;
    float r = x - __uint_as_float(hi << 16);
    unsigned v = __float_as_uint(r);
    unsigned lo = (v + 0x7fffu + ((v >> 16) & 1u)) >> 16;
    return (hi << 16) | lo;
}
__device__ __forceinline__ float unpack_hl(unsigned p) {
    return __uint_as_float(p & 0xffff0000u) + __uint_as_float(p << 16);
}
__device__ __forceinline__ unsigned short pack_bf16(float x) {
    unsigned u = __float_as_uint(x);
    return (unsigned short)((u + 0x7fffu + ((u >> 16) & 1u)) >> 16);
}
__device__ __forceinline__ float bf16f(unsigned short s) {
    return __uint_as_float(((unsigned)s) << 16);
}

// B-side split (activations packed u32 in LDS)
__device__ __forceinline__ void split_frag(uint4 a, uint4 b, short8& hi, short8& lo) {
    unsigned w[8] = {a.x, a.y, a.z, a.w, b.x, b.y, b.z, b.w};
    union U { unsigned u[4]; short8 s; } h, l;
    #pragma unroll
    for (int j = 0; j < 4; ++j) {
        h.u[j] = (w[2*j] >> 16)      | (w[2*j+1] & 0xffff0000u);
        l.u[j] = (w[2*j] & 0xffffu)  | (w[2*j+1] << 16);
    }
    hi = h.s; lo = l.s;
}

// B tile addr v2 (u32 units): kblock-major + 16-row rotation per kblock
__device__ __forceinline__ int taddr2(int row, int kw) {
    int kb = kw >> 2;
    return (kb << 9) + (((row + (kb << 4)) & 127) << 2) + (kw & 3);
}
// word index of element (pixel p, k-channel c) in a per-batch image with nkt k-tiles
__device__ __forceinline__ long bwidx2(int p, int c, int nkt) {
    return ((long)((p >> 7) * nkt + (c >> 5)) << 12) + taddr2(p & 127, c & 31);
}

typedef __attribute__((address_space(3))) unsigned lds_u32_t;
typedef __attribute__((address_space(1))) const unsigned gbl_u32_t;
__device__ __forceinline__ void gld16(const void* g, unsigned* l) {
    __builtin_amdgcn_global_load_lds((gbl_u32_t*)g, (lds_u32_t*)l, 16, 0, 0);
}

// ---------------- MFMA GEMM with fused epilogues ----------------
// MODE 1: bf16 store (+ scalar bias[row])        -> outv = ushort* (linear)
// MODE 2: LSTM fuse: rows c*4+gate; stv=Cst(f32 linear), outv=Ha image (packed)
// MODE 3: final fuse: rows c*4+gate(3+pad); stv=mp image, outv=Hb image, Hout opt fp32 linear
// B-source: m0>=m_split -> imgB(kofs 0); k0>=k_split -> imgB(kofs k_split); else imgA.
// Both imgA/imgB are kblock-major B-tile images (packed hi/lo u32), DMA-staged.
// LO0: imgB region has lo==0 -> skip the ahi*blo MFMA pass there.
template<int MODE, int LO0>
__global__ __launch_bounds__(256, 2) void gemm_mfma(
    const unsigned* __restrict__ Wp, const float* __restrict__ bias,
    const unsigned* __restrict__ imgA, long wA,
    const unsigned* __restrict__ imgB, long wB, int nktB,
    int k_split, int m_split,
    void* __restrict__ outv, void* __restrict__ stv, float* __restrict__ Hout,
    int M, int K)
{
    __shared__ __align__(16) unsigned As[5120];   // 20480 B weight tile image
    __shared__ __align__(16) unsigned Bs[4096];   // 16384 B activation tile image

    const int b  = blockIdx.z;
    const int n0 = blockIdx.x * 128;
    const int m0 = blockIdx.y * 128;
    const int t  = threadIdx.x;
    const int lane = t & 63;
    const int w  = t >> 6;
    const int wm = w & 1, wn = w >> 1;
    const int g  = lane >> 4, pl = lane & 15;
    const int cb = ((g + (pl >> 2)) & 3) << 4;    // A-plane 16B-block rotation

    f32x4 acc[4][4] = {};

    for (int k0 = 0; k0 < K; k0 += 32) {
        // stage A (weights): 5 DMA rounds
        {
            const char* gA = (const char*)Wp +
                (size_t)((m0 >> 7) * (K >> 5) + (k0 >> 5)) * 20480;
            #pragma unroll
            for (int r = 0; r < 5; ++r)
                gld16(gA + r * 4096 + t * 16, As + r * 1024 + t * 4);
        }
        // stage B (activation image): exactly 4 DMA rounds (16 KB tile)
        const bool useB = (m0 >= m_split) || (k0 >= k_split);
        {
            const int kc = useB ? (k0 - ((m0 >= m_split) ? 0 : k_split)) : k0;
            const unsigned* img = useB ? imgB : imgA;
            const long bw = useB ? wB : wA;
            const int nkt = useB ? nktB : 4;
            const char* gB = (const char*)(img + (long)b * bw +
                ((long)((n0 >> 7) * nkt + (kc >> 5)) << 12));
            #pragma unroll
            for (int r = 0; r < 4; ++r)
                gld16(gB + r * 4096 + t * 16, Bs + r * 1024 + t * 4);
        }
        __syncthreads();

        short8 ahi[4], alo[4], bhi[4], blo[4];
        #pragma unroll
        for (int mt = 0; mt < 4; ++mt) {
            int row = 64 * wm + 16 * mt + pl;
            const char* pa = (const char*)As + row * 80 + cb;
            ahi[mt] = *(const short8*)pa;
            alo[mt] = *(const short8*)(pa + 10240);
        }
        #pragma unroll
        for (int nt = 0; nt < 4; ++nt) {
            int prow = 64 * wn + 16 * nt + pl;
            uint4 w0 = *(const uint4*)(Bs + taddr2(prow, 8 * g));
            uint4 w1 = *(const uint4*)(Bs + taddr2(prow, 8 * g + 4));
            split_frag(w0, w1, bhi[nt], blo[nt]);
        }
        const bool skiplo = LO0 && useB;
        if (skiplo) {
            #pragma unroll
            for (int mt = 0; mt < 4; ++mt)
                #pragma unroll
                for (int nt = 0; nt < 4; ++nt) {
                    acc[mt][nt] = __builtin_amdgcn_mfma_f32_16x16x32_bf16(ahi[mt], bhi[nt], acc[mt][nt], 0, 0, 0);
                    acc[mt][nt] = __builtin_amdgcn_mfma_f32_16x16x32_bf16(alo[mt], bhi[nt], acc[mt][nt], 0, 0, 0);
                }
        } else {
            #pragma unroll
            for (int mt = 0; mt < 4; ++mt)
                #pragma unroll
                for (int nt = 0; nt < 4; ++nt) {
                    acc[mt][nt] = __builtin_amdgcn_mfma_f32_16x16x32_bf16(ahi[mt], bhi[nt], acc[mt][nt], 0, 0, 0);
                    acc[mt][nt] = __builtin_amdgcn_mfma_f32_16x16x32_bf16(ahi[mt], blo[nt], acc[mt][nt], 0, 0, 0);
                    acc[mt][nt] = __builtin_amdgcn_mfma_f32_16x16x32_bf16(alo[mt], bhi[nt], acc[mt][nt], 0, 0, 0);
                }
        }
        __syncthreads();
    }

    if (MODE == 1) {
        #pragma unroll
        for (int mt = 0; mt < 4; ++mt)
            #pragma unroll
            for (int r = 0; r < 4; ++r) {
                int row = m0 + 64 * wm + 16 * mt + 4 * g + r;
                float bb = bias[row];
                #pragma unroll
                for (int nt = 0; nt < 4; ++nt) {
                    int col = n0 + 64 * wn + 16 * nt + pl;
                    ((unsigned short*)outv)[((long)b * M + row) * HW + col] =
                        pack_bf16(acc[mt][nt][r] + bb);
                }
            }
    } else {
        // rows interleaved c*4+gate: one thread's f32x4 = all 4 gates of channel c
        const float4* bias4 = (const float4*)bias;
        unsigned* Hp = (unsigned*)outv;
        #pragma unroll
        for (int mt = 0; mt < 4; ++mt) {
            int c = (m0 >> 2) + 16 * wm + 4 * mt + g;
            float4 bb = bias4[c];
            #pragma unroll
            for (int nt = 0; nt < 4; ++nt) {
                int p = n0 + 64 * wn + 16 * nt + pl;
                long lidx = (long)b * PIX + (long)c * HW + p;       // linear (Cst, Hout)
                long widx = (long)b * WI + bwidx2(p, c, 4);         // image (Ha/Hb/mp)
                float v0 = acc[mt][nt][0] + bb.x;
                float v1 = acc[mt][nt][1] + bb.y;
                float v2 = acc[mt][nt][2] + bb.z;
                float v3 = acc[mt][nt][3] + bb.w;
                if (MODE == 2) {
                    float* Cst = (float*)stv;
                    float cc = Cst[lidx] * sigf(v0) + sigf(v1) * tanhf_fast(v2);
                    Cst[lidx] = cc;
                    Hp[widx] = pack_hl(sigf(v3) * tanhf_fast(cc));
                } else {
                    unsigned* mp = (unsigned*)stv;
                    float ot = sigf(v0), gt = tanhf_fast(v1), it = sigf(v2);
                    float mo = unpack_hl(mp[widx]);
                    float mn = gt * it + (1.0f - it) * mo;
                    mp[widx] = pack_hl(mn);
                    float hv = ot * mn;
                    Hp[widx] = pack_hl(hv);
                    if (Hout) Hout[lidx] = hv;
                }
            }
        }
    }
}

// ---------------- attention: VKM bf16 [16][640][1024] -> Zimg (kblock-major, lo=0) ----------------
// block = (b, c-quad): 4 channels per block, dense uint4 stores
__global__ __launch_bounds__(1024) void attn_kernel(
    const unsigned short* __restrict__ VKM, unsigned* __restrict__ Zimg)
{
    __shared__ float qs[4][32 * 33];
    const int tid = threadIdx.x;
    const int b = blockIdx.x >> 5, cq = blockIdx.x & 31;
    const int c0 = cq << 2;
    const long base = (long)b * 640 * HW;

    #pragma unroll
    for (int cc = 0; cc < 4; ++cc)
        qs[cc][(tid >> 5) * 33 + (tid & 31)] =
            bf16f(VKM[base + (long)(256 + c0 + cc) * HW + tid]);
    __syncthreads();

    const int i = tid >> 5, j = tid & 31;
    uint4 oh, om;
    unsigned* ohw = (unsigned*)&oh;
    unsigned* omw = (unsigned*)&om;
    #pragma unroll
    for (int cc = 0; cc < 4; ++cc) {
        const long cbs = base + (long)(c0 + cc) * HW;
        float qhT = qs[cc][j * 33 + i];
        float vh  = bf16f(VKM[cbs + tid]);
        float kh  = bf16f(VKM[cbs + 128l * HW + tid]);
        float km  = bf16f(VKM[cbs + 384l * HW + tid]);
        float vm  = bf16f(VKM[cbs + 512l * HW + tid]);

        float sh = kh * qhT, sm = qhT * km;
        float mh = sh, mm = sm;
        #pragma unroll
        for (int o = 16; o > 0; o >>= 1) {
            mh = fmaxf(mh, __shfl_xor(mh, o, 32));
            mm = fmaxf(mm, __shfl_xor(mm, o, 32));
        }
        float eh = __expf(sh - mh), em = __expf(sm - mm);
        float s1 = eh, s2 = em;
        #pragma unroll
        for (int o = 16; o > 0; o >>= 1) {
            s1 += __shfl_xor(s1, o, 32);
            s2 += __shfl_xor(s2, o, 32);
        }
        ohw[cc] = ((unsigned)pack_bf16(vh * (eh / s1))) << 16;
        omw[cc] = ((unsigned)pack_bf16(vm * (em / s2))) << 16;
    }
    const int kt = c0 >> 5, kb = (c0 & 31) >> 2;
    const int phys = ((tid & 127) + (kb << 4)) & 127;
    long u4 = ((long)b << 16) + ((long)(tid >> 7) << 13) + (kb << 7) + phys;
    ((uint4*)Zimg)[u4 + ((long)kt << 10)]       = oh;   // zh at k=c0..c0+3
    ((uint4*)Zimg)[u4 + ((long)(kt + 4) << 10)] = om;   // zm at k=c0+128..
}

// ---------------- pack x into B-image format: dest-linear streaming ----------------
// one uint4 per thread; dest index == idx (one-shot) — fully coalesced both sides
// x layout is [B][T][C][HW] (batch-major)
__global__ __launch_bounds__(256) void pack_x(
    const float* __restrict__ x, uint4* __restrict__ Xp, int tstart, int oneshot)
{
    long idx = (long)blockIdx.x * 256 + threadIdx.x;
    int t = tstart + (int)(idx >> 19);
    long rest = idx & ((1l << 19) - 1);
    int b = (int)(rest >> 15);
    int v = (int)(rest & 32767);            // ptile*4096 + kt*1024 + kb*128 + phys
    int kb = (v >> 7) & 7, phys = v & 127;
    int row = (phys - (kb << 4)) & 127;
    int p = ((v >> 12) << 7) + row;
    int c = (((v >> 10) & 3) << 5) + (kb << 2);
    const float* xs = x + (((long)b * TT + t) * CC + c) * HW + p;
    uint4 o;
    o.x = pack_hl(xs[0]);
    o.y = pack_hl(xs[HW]);
    o.z = pack_hl(xs[2 * HW]);
    o.w = pack_hl(xs[3 * HW]);
    Xp[oneshot ? idx : rest] = o;
}

// ---------------- one-shot setup: build pre-swizzled hi/lo weight tile images ----------------
__device__ __forceinline__ void wimg(unsigned short* img, int Ktiles, int r, int k, float v) {
    int tile = (r >> 7) * Ktiles + (k >> 5);
    int row = r & 127, ks = k & 31;
    unsigned short* p = img + (size_t)tile * 10240;   // 10240 shorts = 20480 B per tile
    int off = row * 40 + ((((ks >> 3) + (row >> 2)) & 3) << 3) + (ks & 7);
    unsigned u = __float_as_uint(v);
    unsigned short hi = (unsigned short)((u + 0x7fffu + ((u >> 16) & 1u)) >> 16);
    float rr = v - __uint_as_float((unsigned)hi << 16);
    unsigned u2 = __float_as_uint(rr);
    unsigned short lo = (unsigned short)((u2 + 0x7fffu + ((u2 >> 16) & 1u)) >> 16);
    p[off] = hi;
    p[off + 5120] = lo;                               // lo plane at +10240 B
}

__global__ __launch_bounds__(256) void setup_all(
    const float* __restrict__ W5, const float* __restrict__ W8, const float* __restrict__ b8,
    unsigned short* __restrict__ Wp5i,
    unsigned short* __restrict__ Wgi, float* __restrict__ bg4,
    unsigned short* __restrict__ Woi, float* __restrict__ bo4)
{
    int idx = blockIdx.x * 256 + threadIdx.x;
    if (idx < 81920) {                       // W5 [640][128] -> Wp5 image (Ktiles=4)
        int r = idx >> 7, k = idx & 127;
        wimg(Wp5i, 4, r, k, W5[idx]);
        return;
    }
    idx -= 81920;
    if (idx < 131072) {                      // Wg: rows c*4+gate, convs 10..13, K=256 (Ktiles=8)
        int rr = idx >> 8, k = idx & 255;
        int c = rr >> 2, gg = rr & 3;
        wimg(Wgi, 8, rr, k, W8[((long)(4 + gg) * 128 + c) * 256 + k]);
        if (k == 0) bg4[rr] = b8[(4 + gg) * 128 + c];
        return;
    }
    idx -= 131072;                           // Wo: 512 rows x 384, conv6 folded (Ktiles=12)
    if (idx >= 512 * 384) return;
    int rr = idx / 384, k = idx - rr * 384;
    int c = rr >> 2, gg = rr & 3;
    float wv = 0.0f;
    if (gg < 3) {
        const float* wr = W8 + ((long)(1 + gg) * 128 + c) * 256;
        if (k < 128) {
            wv = wr[k];
        } else {
            int i = k - 128;
            float s = 0.0f;
            for (int j = 0; j < 128; ++j)
                s += wr[128 + j] * W8[(long)j * 256 + i];   // Wz = W8[0]
            wv = s;
        }
    }
    wimg(Woi, 12, rr, k, wv);
    if (k == 0) {
        float bb = 0.0f;
        if (gg < 3) {
            bb = b8[(1 + gg) * 128 + c];
            const float* wr = W8 + ((long)(1 + gg) * 128 + c) * 256;
            for (int j = 0; j < 128; ++j) bb += wr[128 + j] * b8[j];  // bz = b8[0]
        }
        bo4[rr] = bb;
    }
}

extern "C" void kernel_launch(void* const* d_in, const int* in_sizes, int n_in,
                              void* d_out, int out_size, void* d_ws, size_t ws_size,
                              hipStream_t stream)
{
    const float* x  = (const float*)d_in[0];   // [16][16][128][1024]  (B-major)
    const float* c0 = (const float*)d_in[1];
    const float* W5 = (const float*)d_in[2];   // [640][128]
    const float* b5 = (const float*)d_in[3];   // [640]
    const float* W8 = (const float*)d_in[4];   // [8][128][256]
    const float* b8 = (const float*)d_in[5];   // [8][128]
    float* out = (float*)d_out;

    const long S = STOT;
    unsigned* Ha   = (unsigned*)d_ws;                   // 16*WI (image)
    unsigned* Hb   = Ha + 16l * WI;                     // 16*WI (image)
    unsigned* mp   = Hb + 16l * WI;                     // 16*WI (image)
    float*    Cst  = (float*)(mp + 16l * WI);           // S fp32 linear
    unsigned short* Wp5i = (unsigned short*)(Cst + S);  // 20 tiles * 10240 shorts
    unsigned short* Wgi  = Wp5i + 20 * 10240;           // 32 tiles
    unsigned short* Woi  = Wgi + 32 * 10240;            // 48 tiles
    float*    bg4  = (float*)(Woi + 48 * 10240);        // 512
    float*    bo4  = bg4 + 512;                         // 512
    unsigned short* VKM = (unsigned short*)(bo4 + 512); // 5S bf16 linear
    unsigned* Zimg = (unsigned*)(VKM + 5 * S);          // 16*WZ (image)
    unsigned* Xp   = Zimg + 16l * WZ;                   // 16*XW full, or XW slot

    const bool havex =
        ((char*)(Xp + 16l * XW) - (char*)d_ws) <= (long)ws_size;

    hipMemsetAsync(Hb, 0, 16l * WI * 4, stream);
    hipMemsetAsync(mp, 0, 16l * WI * 4, stream);
    hipMemcpyAsync(Cst, c0, S * sizeof(float), hipMemcpyDeviceToDevice, stream);

    setup_all<<<1600, dim3(256), 0, stream>>>(W5, W8, b8, Wp5i, Wgi, bg4, Woi, bo4);
    if (havex)
        pack_x<<<32768, dim3(256), 0, stream>>>(x, (uint4*)Xp, 0, 1);

    const int BIG = 1 << 30;
    const dim3 blk(256);
    for (int t = 0; t < TT; ++t) {
        if (!havex)
            pack_x<<<2048, dim3(256), 0, stream>>>(x, (uint4*)Xp, t, 0);
        const unsigned* Xpt = Xp + (havex ? (long)t * XW : 0l);

        // gates = Wg * [Hb ; x_t], fused LSTM -> Cst, Ha image  (M=512, K=256)
        gemm_mfma<2, 0><<<dim3(8, 4, 16), blk, 0, stream>>>(
            (const unsigned*)Wgi, bg4, Hb, (long)WI, Xpt, (long)WI, 4,
            128, BIG, Ha, Cst, nullptr, 512, 256);

        // vh,kh,qh (Ha) + km,vm (mp)   (M=640, K=128) -> VKM bf16 linear
        gemm_mfma<1, 0><<<dim3(8, 5, 16), blk, 0, stream>>>(
            (const unsigned*)Wp5i, b5, Ha, (long)WI, mp, (long)WI, 4,
            BIG, 384, VKM, nullptr, nullptr, 640, 128);

        attn_kernel<<<512, dim3(1024), 0, stream>>>(VKM, Zimg);

        // o,g,i = Wo * [Ha ; Zimg] (conv6 folded), fused final -> mp, Hb (+out)
        gemm_mfma<3, 1><<<dim3(8, 4, 16), blk, 0, stream>>>(
            (const unsigned*)Woi, bo4, Ha, (long)WI, Zimg, (long)WZ, 8,
            128, BIG, Hb, mp, (t == TT - 1) ? out : nullptr, 512, 384);
    }
}